// Round 3
// baseline (574.508 us; speedup 1.0000x reference)
//
#include <hip/hip_runtime.h>
#include <hip/hip_bf16.h>
#include <cstdint>
#include <cstddef>

// Problem constants (BahdanauAttention): B=32, S=2048, d=512, M=512, K=2d=1024
#define B_   32
#define S_   2048
#define D_   512
#define K2D  1024
#define M_   512

// ws layout (float indices):
#define WS_SCORES 0
#define WS_EXPS   65536
#define WS_DENOM  131072
#define WS_WQ     131104
#define WS_FLAG   147488
#define WS_UAB16  147520            // 1 MB of bf16 Ua_w (512x1024), 16B-aligned
#define WS_NEED_BYTES (147520 * 4 + 1048576)

typedef __attribute__((ext_vector_type(8))) short bf16x8;   // 8 bf16 = 4 VGPRs
typedef __attribute__((ext_vector_type(4))) float f32x4;    // MFMA C/D frag

// tanh via exp2 pipe: tanh(x) = 1 - 2/(e^{2x}+1).  Handles +-inf correctly.
__device__ __forceinline__ float tanh_fast(float x) {
    float e = __expf(2.0f * x);
    return 1.0f - 2.0f * __builtin_amdgcn_rcpf(e + 1.0f);
}

union Pack8 { bf16x8 v; __hip_bfloat162 h[4]; };
__device__ __forceinline__ bf16x8 cvt8(float4 a, float4 b) {
    Pack8 p;
    p.h[0] = __float22bfloat162_rn(make_float2(a.x, a.y));
    p.h[1] = __float22bfloat162_rn(make_float2(a.z, a.w));
    p.h[2] = __float22bfloat162_rn(make_float2(b.x, b.y));
    p.h[3] = __float22bfloat162_rn(make_float2(b.z, b.w));
    return p.v;
}

// ---------------- init: zero scores/denom/out/flag ----------------
__global__ void k_zero(float* __restrict__ scores, float* __restrict__ denom,
                       float* __restrict__ out, int* __restrict__ flag) {
    int tid = blockIdx.x * 256 + threadIdx.x;
    if (tid < 65536) scores[tid] = 0.f;
    else if (tid < 65568) denom[tid - 65536] = 0.f;
    if (tid < 32768) out[tid] = 0.f;
    if (tid == 65568) *flag = 0;
}

// ---------------- mask dtype probe (bool-bytes vs int32) ----------------
// Reads only the first 16384 u32 words (64 KB) — safe under either dtype.
__global__ void k_flag(const unsigned int* __restrict__ maskw, int* __restrict__ flag) {
    int base = (blockIdx.x * 256 + threadIdx.x) * 4;
    int f = 0;
#pragma unroll
    for (int i = 0; i < 4; ++i)
        if (maskw[base + i] > 1u) f = 1;
    if (f) atomicOr(flag, 1);
}

// ---------------- Ua_w fp32 -> bf16 ----------------
__global__ __launch_bounds__(256) void k_cvtB(const float* __restrict__ Ua_w,
                                              ushort* __restrict__ Ub16) {
    int i = (blockIdx.x * 256 + threadIdx.x) * 8;   // 512*1024/8 = 65536 threads
    float4 a = *(const float4*)(Ua_w + i);
    float4 b = *(const float4*)(Ua_w + i + 4);
    *(bf16x8*)(Ub16 + i) = cvt8(a, b);
}

// ---------------- wq = query @ Wa_w^T + Wa_b ----------------
__global__ __launch_bounds__(256) void k_wq(const float* __restrict__ query,
                                            const float* __restrict__ Wa_w,
                                            const float* __restrict__ Wa_b,
                                            float* __restrict__ wq) {
    int tid = blockIdx.x * 256 + threadIdx.x;   // 0..16383
    int b = tid >> 9, m = tid & 511;
    const float4* q = (const float4*)(query + (size_t)b * D_);
    const float4* w = (const float4*)(Wa_w + (size_t)m * D_);
    float acc = 0.f;
    for (int i = 0; i < D_ / 4; ++i) {
        float4 qv = q[i], wv = w[i];
        acc = fmaf(qv.x, wv.x, acc);
        acc = fmaf(qv.y, wv.y, acc);
        acc = fmaf(qv.z, wv.z, acc);
        acc = fmaf(qv.w, wv.w, acc);
    }
    wq[tid] = acc + Wa_b[m];
}

// ---------------- MFMA scores: uk-GEMM(bf16) + tanh + Va reduce ----------
// A (keys) staged via LDS (needs fp32->bf16 cvt share). B (Ua_w) fragments
// loaded DIRECTLY global->VGPR (K-major layout == B-frag layout); bf16 from
// ws if available (USEB16=1), else fp32+cvt. No Bs in LDS at all.
// Block 128s x 128m, BK=64, 4 waves 2x2, wave = 4x4 of 16x16x32 frags.
// 1-D grid 2048 with XCD swizzle: the 4 m-sibling blocks of one s-chunk land
// on the same XCD (h%8) so keys re-reads hit that XCD's L2.
template <int USEB16>
__global__ __launch_bounds__(256, 3) void k_scores(const float* __restrict__ keys,
                                                   const float* __restrict__ Ua_w,
                                                   const ushort* __restrict__ Ub16,
                                                   const float* __restrict__ Ua_b,
                                                   const float* __restrict__ Va_w,
                                                   const float* __restrict__ wq,
                                                   float* __restrict__ scores) {
    __shared__ ushort As[128 * 72];   // [row][72]: 64 k + 8 pad; 144B rows

    const int h    = blockIdx.x;
    const int xcd  = h & 7, slot = h >> 3;
    const int mj   = slot & 3;
    const int grp  = xcd + 8 * (slot >> 2);      // 0..511
    const int b    = grp >> 4;
    const int s0   = (grp & 15) * 128;
    const int m0   = mj * 128;

    const int t = threadIdx.x;
    const int wave = t >> 6, lane = t & 63;
    const int q = lane >> 4, r = lane & 15;
    const int sw = (wave >> 1) * 64, mw = (wave & 1) * 64;
    const int rb = t >> 3;     // staging row 0..31 (+32p)
    const int kq = t & 7;      // staging k-chunk (8 floats)

    const float*  Ab   = keys + ((size_t)b * S_ + s0 + rb) * K2D + kq * 8;
    const ushort* Bb16 = Ub16 + (size_t)(m0 + mw + r) * K2D;
    const float*  Bb32 = Ua_w + (size_t)(m0 + mw + r) * K2D;
    ushort* aw = &As[rb * 72 + kq * 8];

    f32x4 acc[4][4];
#pragma unroll
    for (int i = 0; i < 4; ++i)
#pragma unroll
        for (int j = 0; j < 4; ++j) acc[i][j] = (f32x4){0.f, 0.f, 0.f, 0.f};

    for (int kt = 0; kt < K2D / 64; ++kt) {
        const int ko = kt * 64;
        // ---- stage A tile (128x64) as bf16 into LDS ----
#pragma unroll
        for (int p = 0; p < 4; ++p) {
            const float* sa = Ab + (size_t)(p * 32) * K2D + ko;
            float4 a0 = *(const float4*)sa;
            float4 a1 = *(const float4*)(sa + 4);
            *(bf16x8*)(aw + p * 32 * 72) = cvt8(a0, a1);
        }
        __syncthreads();
#pragma unroll
        for (int ks = 0; ks < 2; ++ks) {
            bf16x8 af[4], bfr[4];
#pragma unroll
            for (int i = 0; i < 4; ++i)
                af[i] = *(const bf16x8*)&As[(sw + i * 16 + r) * 72 + ks * 32 + q * 8];
#pragma unroll
            for (int j = 0; j < 4; ++j) {
                const int off = j * 16 * K2D + ko + ks * 32 + q * 8;
                if (USEB16) {
                    bfr[j] = *(const bf16x8*)(Bb16 + off);
                } else {
                    float4 b0 = *(const float4*)(Bb32 + off);
                    float4 b1 = *(const float4*)(Bb32 + off + 4);
                    bfr[j] = cvt8(b0, b1);
                }
            }
#pragma unroll
            for (int i = 0; i < 4; ++i)
#pragma unroll
                for (int j = 0; j < 4; ++j)
                    acc[i][j] = __builtin_amdgcn_mfma_f32_16x16x32_bf16(
                        af[i], bfr[j], acc[i][j], 0, 0, 0);
        }
        __syncthreads();
    }

    // Epilogue. C/D layout: col(m)=lane&15, row(s)=q*4+reg.
    float vaw[4], wqb[4];
#pragma unroll
    for (int j = 0; j < 4; ++j) {
        int m = m0 + mw + 16 * j + r;
        vaw[j] = Va_w[m];
        wqb[j] = wq[b * M_ + m] + Ua_b[m];
    }
    float* red = (float*)As;           // overlay: 128 x 33 floats = 16.9 KB
    const int col = (wave & 1) * 16 + r;
#pragma unroll
    for (int i = 0; i < 4; ++i) {
#pragma unroll
        for (int rg = 0; rg < 4; ++rg) {
            int sl = sw + 16 * i + 4 * q + rg;
            float p = 0.f;
#pragma unroll
            for (int j = 0; j < 4; ++j)
                p += vaw[j] * tanh_fast(acc[i][j][rg] + wqb[j]);
            red[sl * 33 + col] = p;    // every (sl,col) written exactly once
        }
    }
    __syncthreads();
    if (t < 128) {
        float sum = 0.f;
#pragma unroll
        for (int c = 0; c < 32; ++c) sum += red[t * 33 + c];
        atomicAdd(&scores[(size_t)b * S_ + s0 + t], sum);
    }
}

// ---------------- masked exp + per-b denom ----------------
// |score| <= sum|Va_w| ~ 55.5 < 88, so no max-subtraction needed.
__global__ __launch_bounds__(256) void k_softmax(const float* __restrict__ scores,
                                                 const void* __restrict__ mask,
                                                 const int* __restrict__ flag,
                                                 float* __restrict__ exps,
                                                 float* __restrict__ denom) {
    const int b = blockIdx.x, t = threadIdx.x;
    const bool bytemode = (*flag) != 0;
    const int* mi = (const int*)mask;
    const unsigned char* mb = (const unsigned char*)mask;
    float lsum = 0.f;
#pragma unroll
    for (int i = 0; i < 8; ++i) {
        int s = i * 256 + t;
        size_t idx = (size_t)b * S_ + s;
        bool m = bytemode ? (mb[idx] != 0) : (mi[idx] != 0);
        float v = m ? 0.f : expf(scores[idx]);
        exps[idx] = v;
        lsum += v;
    }
#pragma unroll
    for (int off = 32; off > 0; off >>= 1) lsum += __shfl_down(lsum, off, 64);
    __shared__ float wsum[4];
    if ((t & 63) == 0) wsum[t >> 6] = lsum;
    __syncthreads();
    if (t == 0) denom[b] = wsum[0] + wsum[1] + wsum[2] + wsum[3];
}

// ---------------- context = (exp/denom) @ keys ----------------
__global__ __launch_bounds__(256) void k_context(const float* __restrict__ keys,
                                                 const float* __restrict__ exps,
                                                 const float* __restrict__ denom,
                                                 float* __restrict__ out) {
    __shared__ float w[64];
    const int s0 = blockIdx.x * 64;
    const int b  = blockIdx.y;
    const int t  = threadIdx.x;
    if (t < 64) w[t] = exps[(size_t)b * S_ + s0 + t];
    __syncthreads();
    const float4* kp = (const float4*)(keys + ((size_t)b * S_ + s0) * K2D);
    float4 acc = {0.f, 0.f, 0.f, 0.f};
#pragma unroll 8
    for (int s = 0; s < 64; ++s) {
        float ws = w[s];
        float4 kv = kp[(size_t)s * 256 + t];
        acc.x = fmaf(ws, kv.x, acc.x);
        acc.y = fmaf(ws, kv.y, acc.y);
        acc.z = fmaf(ws, kv.z, acc.z);
        acc.w = fmaf(ws, kv.w, acc.w);
    }
    float inv = 1.0f / denom[b];
    atomicAdd(&out[b * 1024 + t * 4 + 0], acc.x * inv);
    atomicAdd(&out[b * 1024 + t * 4 + 1], acc.y * inv);
    atomicAdd(&out[b * 1024 + t * 4 + 2], acc.z * inv);
    atomicAdd(&out[b * 1024 + t * 4 + 3], acc.w * inv);
}

extern "C" void kernel_launch(void* const* d_in, const int* in_sizes, int n_in,
                              void* d_out, int out_size, void* d_ws, size_t ws_size,
                              hipStream_t stream) {
    const float* query = (const float*)d_in[0];
    const float* keys  = (const float*)d_in[1];
    const void*  mask  = d_in[2];
    const float* Wa_w  = (const float*)d_in[3];
    const float* Wa_b  = (const float*)d_in[4];
    const float* Ua_w  = (const float*)d_in[5];
    const float* Ua_b  = (const float*)d_in[6];
    const float* Va_w  = (const float*)d_in[7];
    // Va_b is softmax-invariant -> dropped.

    float*  wsf    = (float*)d_ws;
    float*  scores = wsf + WS_SCORES;
    float*  exps   = wsf + WS_EXPS;
    float*  denom  = wsf + WS_DENOM;
    float*  wq     = wsf + WS_WQ;
    int*    flag   = (int*)(wsf + WS_FLAG);
    ushort* Ub16   = (ushort*)(wsf + WS_UAB16);
    float*  out    = (float*)d_out;

    const bool big = ws_size >= (size_t)WS_NEED_BYTES;

    k_zero<<<257, 256, 0, stream>>>(scores, denom, out, flag);
    k_flag<<<16, 256, 0, stream>>>((const unsigned int*)mask, flag);
    k_wq<<<64, 256, 0, stream>>>(query, Wa_w, Wa_b, wq);
    if (big) {
        k_cvtB<<<256, 256, 0, stream>>>(Ua_w, Ub16);
        k_scores<1><<<2048, 256, 0, stream>>>(keys, Ua_w, Ub16, Ua_b, Va_w, wq, scores);
    } else {
        k_scores<0><<<2048, 256, 0, stream>>>(keys, Ua_w, Ub16, Ua_b, Va_w, wq, scores);
    }
    k_softmax<<<B_, 256, 0, stream>>>(scores, mask, flag, exps, denom);
    k_context<<<dim3(S_ / 64, B_), 256, 0, stream>>>(keys, exps, denom, out);
}